// Round 2
// baseline (445.736 us; speedup 1.0000x reference)
//
#include <hip/hip_runtime.h>
#include <hip/hip_fp16.h>
#include <math.h>

// Fan-beam CT forward projection — analytic Siddon, crossing-parallel.
//
// R6/R7: lanes [0,nx) own x-crossings (read row-major corner table P,
// contiguous in x), lanes [nx,nx+ny) own y-crossings (read TRANSPOSED
// corner table PT, contiguous in y). Successor of each crossing is O(1):
// min(next own-AP element, first other-AP element after cur), count found
// by a seeded +-1 fixup. Segments are bit-identical to the sorted merge
// (same fmaf(k,s,b) values, tie-break X-before-Y).
//
// R7 fix: lanes with no successor (global max / inactive) previously left
// nxt=3e38 flowing into mid/ixp -> inf-inf = NaN -> fmaf(0,NaN,acc)
// poisoned acc; the isnan() output guard then wrote 0 for whole rays
// (absmax 55 vs 1.1). Clamp nxt=cur for invalid lanes: diff=0, wf=0,
// all arithmetic finite. Valid lanes unchanged.

constexpr int IMG_N  = 256;
constexpr int NDET   = 368;
constexpr int NVIEW  = 180;
constexpr int NSAMP  = 2 * IMG_N + 1;       // 513
constexpr int DV     = NDET * NVIEW;        // 66240
constexpr int NITER  = (NSAMP + 63) / 64;   // 9 (fallback kernel)

struct __align__(8) Corner { __half2 ab; __half2 cd; };

// ws layout: P (row-major corners) | PT (transposed corners) | rt | kr
constexpr size_t PACK_BYTES = (size_t)IMG_N * IMG_N * sizeof(Corner); // 512 KiB
constexpr size_t PT_OFF     = PACK_BYTES;
constexpr size_t RT_OFF     = 2 * PACK_BYTES;                         // 1 MiB
constexpr size_t RT_BYTES   = (size_t)DV * 3 * sizeof(float4);        // 3.2 MB
constexpr size_t KR_OFF     = RT_OFF + RT_BYTES;
constexpr size_t KR_BYTES   = (size_t)DV * sizeof(int2);
constexpr size_t WS_NEEDED  = KR_OFF + KR_BYTES;                      // ~4.7 MB

__device__ __forceinline__ double valAP(double A, double s, double inv, int k) {
    return (A + s * (double)k) * inv;
}

// ---- corner packs ----
// P [y*256+x]: ab=(v00,v01) cd=(v10,v11)   (row-major: contiguous in x)
// PT[x*256+y]: ab=(v00,v10) cd=(v01,v11)   (col-major: contiguous in y)
__global__ __launch_bounds__(256) void pack_kernel(
    const float* __restrict__ img, Corner* __restrict__ P, Corner* __restrict__ PT)
{
    const int idx = blockIdx.x * 256 + threadIdx.x;
    if (idx < IMG_N * IMG_N) {
        const int y  = idx >> 8;
        const int x  = idx & 255;
        const int x1 = min(x + 1, IMG_N - 1);
        const int y1 = min(y + 1, IMG_N - 1);
        Corner c;
        c.ab = __floats2half2_rn(img[y * IMG_N + x],  img[y * IMG_N + x1]);
        c.cd = __floats2half2_rn(img[y1 * IMG_N + x], img[y1 * IMG_N + x1]);
        P[idx] = c;
    } else {
        const int k  = idx - IMG_N * IMG_N;
        const int x  = k >> 8;
        const int y  = k & 255;
        const int x1 = min(x + 1, IMG_N - 1);
        const int y1 = min(y + 1, IMG_N - 1);
        Corner c;
        c.ab = __floats2half2_rn(img[y * IMG_N + x],  img[y1 * IMG_N + x]);
        c.cd = __floats2half2_rn(img[y * IMG_N + x1], img[y1 * IMG_N + x1]);
        PT[k] = c;
    }
}

// ---- per-ray geometry (fp64 membership, fp32 folded constants) ----
__global__ __launch_bounds__(256) void geom_kernel(
    float4* __restrict__ rt, int2* __restrict__ kr)
{
    const int idx = blockIdx.x * 256 + threadIdx.x;
    if (idx >= DV) return;
    const int d = idx / NVIEW;
    const int v = idx - d * NVIEW;

    const double d_beta = ((M_PI * 360.0) / (double)NVIEW) / 180.0;
    const double stop   = (double)(NVIEW - 1) * d_beta;
    const double step   = stop / (double)(NVIEW - 1);
    const double beta   = (v == NVIEW - 1) ? stop : (double)v * step;
    const double cb = cos(beta), sb = sin(beta);

    const double sx  = -500.0 * cb;
    const double sy  =  500.0 * sb;
    const double rdy = ((double)d - 183.5) * 2.0;
    const double dx  = cb * 500.0 + sb * rdy;
    const double dy  = (-sb) * 500.0 + cb * rdy;
    const double ddx = dx - sx, ddy = dy - sy;

    double Ax, sxn;
    const double invx = 1.0 / ddx;
    if (invx >= 0.0) { Ax = -128.0 - sx; sxn = 1.0; }
    else             { Ax =  128.0 - sx; sxn = -1.0; }
    double Ay, syn;
    const double invy = 1.0 / ddy;
    if (invy >= 0.0) { Ay = -128.0 - sy; syn = 1.0; }
    else             { Ay =  128.0 - sy; syn = -1.0; }

    const double vx0 = valAP(Ax, sxn, invx, 0), vxN = valAP(Ax, sxn, invx, IMG_N);
    const double vy0 = valAP(Ay, syn, invy, 0), vyN = valAP(Ay, syn, invy, IMG_N);
    double a_min = fmax(vx0, vy0); if (a_min < 0.0) a_min = 0.0;
    double a_max = fmin(vxN, vyN); if (a_max > 1.0) a_max = 1.0;

    const double absdx = fabs(ddx), absdy = fabs(ddy);

    int klox, khix, kloy, khiy;
    {
        double kd = (a_min - vx0) * absdx;
        kd = fmin(fmax(kd, -1.0), 258.0);
        int k = (int)kd; k = max(0, min(k, 256));
        while (k > 0    && valAP(Ax, sxn, invx, k - 1) >= a_min) --k;
        while (k <= 256 && valAP(Ax, sxn, invx, k) < a_min)      ++k;
        klox = k;
        kd = (a_max - vx0) * absdx;
        kd = fmin(fmax(kd, -1.0), 258.0);
        k = (int)kd; k = max(0, min(k, 256));
        while (k > 0    && valAP(Ax, sxn, invx, k - 1) > a_max)  --k;
        while (k <= 256 && valAP(Ax, sxn, invx, k) <= a_max)     ++k;
        khix = k - 1;
        if (klox > khix) { klox = 0; khix = -1; }
    }
    {
        double kd = (a_min - vy0) * absdy;
        kd = fmin(fmax(kd, -1.0), 258.0);
        int k = (int)kd; k = max(0, min(k, 256));
        while (k > 0    && valAP(Ay, syn, invy, k - 1) >= a_min) --k;
        while (k <= 256 && valAP(Ay, syn, invy, k) < a_min)      ++k;
        kloy = k;
        kd = (a_max - vy0) * absdy;
        kd = fmin(fmax(kd, -1.0), 258.0);
        k = (int)kd; k = max(0, min(k, 256));
        while (k > 0    && valAP(Ay, syn, invy, k - 1) > a_max)  --k;
        while (k <= 256 && valAP(Ay, syn, invy, k) <= a_max)     ++k;
        khiy = k - 1;
        if (kloy > khiy) { kloy = 0; khiy = -1; }
    }

    const int nx = khix - klox + 1;
    const int ny = khiy - kloy + 1;
    const double s2d = sqrt(ddx * ddx + ddy * ddy);

    // fp32 folded APs:  X[j] = fma(j, sxf, bxf), j in [0,nx), step > 0
    const double sxd = sxn * invx, syd = syn * invy;           // both > 0
    const double bxd = (Ax + sxn * (double)klox) * invx;
    const double byd = (Ay + syn * (double)kloy) * invy;
    const double invsxd = 1.0 / sxd;
    const double invsyd = 1.0 / syd;

    float4* o = rt + (size_t)idx * 3;
    o[0] = make_float4((float)bxd, (float)sxd, (float)byd, (float)syd);
    o[1] = make_float4((float)invsxd, (float)invsyd, (float)s2d, 0.0f);
    o[2] = make_float4((float)(ddx * (128.0 / 127.5)),
                       (float)(sx  * (128.0 / 127.5) + 127.5),
                       (float)(ddy * (128.0 / 127.5)),
                       (float)(sy  * (128.0 / 127.5) + 127.5));
    kr[idx] = make_int2(nx, ny);
}

// ---- main: one wave per ray, lane = crossing index (X block then Y block)
// Merged order: value-sorted, ties X-before-Y. Each crossing emits the
// segment from itself to its successor; the global max emits nothing.
__global__ __launch_bounds__(256) void fp_siddon(
    const Corner* __restrict__ P,
    const Corner* __restrict__ PT,
    const float4* __restrict__ rt,
    const int2*   __restrict__ kr,
    float*        __restrict__ out)
{
    const int wave = threadIdx.x >> 6;
    const int lane = threadIdx.x & 63;
    const int dv   = __builtin_amdgcn_readfirstlane(blockIdx.x * 4 + wave);

    const float4 A = rt[(size_t)dv * 3 + 0];   // bx, sx, by, sy
    const float4 B = rt[(size_t)dv * 3 + 1];   // invsx, invsy, s2d
    const float4 C = rt[(size_t)dv * 3 + 2];   // cxa, cxb, cya, cyb
    const int2 nn = kr[dv];
    const int nx = nn.x, ny = nn.y;
    const int M = nx + ny;

    float acc = 0.0f;

    for (int base = 0; base < M; base += 64) {
        int c = base + lane;
        const bool act = (c < M);
        c = act ? c : (M - 1);                 // M >= 1 here
        const bool isX = (c < nx);

        float cur, nxt;
        if (isX) {
            cur = fmaf((float)c, A.y, A.x);
            // j = #{Y < cur}: seed then exact fixup
            int j = (int)((cur - A.z) * B.y);
            j = max(0, min(j, ny));
            while (j > 0  && fmaf((float)(j - 1), A.w, A.z) >= cur) --j;
            while (j < ny && fmaf((float)j,       A.w, A.z) <  cur) ++j;
            nxt = 3.0e38f;
            if (c + 1 < nx) nxt = fmaf((float)(c + 1), A.y, A.x);
            if (j < ny)     nxt = fminf(nxt, fmaf((float)j, A.w, A.z));
        } else {
            const int cy = c - nx;
            cur = fmaf((float)cy, A.w, A.z);
            // i = #{X <= cur}  (X-before-Y on ties)
            int i = (int)((cur - A.x) * B.x);
            i = max(0, min(i, nx));
            while (i > 0  && fmaf((float)(i - 1), A.y, A.x) >  cur) --i;
            while (i < nx && fmaf((float)i,       A.y, A.x) <= cur) ++i;
            nxt = 3.0e38f;
            if (cy + 1 < ny) nxt = fmaf((float)(cy + 1), A.w, A.z);
            if (i < nx)      nxt = fminf(nxt, fmaf((float)i, A.y, A.x));
        }

        const bool valid = act && (nxt < 2.9e38f);
        if (!valid) nxt = cur;                 // keep all math finite (NaN guard)
        const float diff = nxt - cur;
        const float mid  = fmaf(diff, 0.5f, cur);
        const float wf   = valid ? diff * B.z : 0.0f;
        const float ixp  = fmaf(mid, C.x, C.y);
        const float iyp  = fmaf(mid, C.z, C.w);

        const float fx0 = floorf(ixp), fy0 = floorf(iyp);
        const float wx1 = ixp - fx0,  wy1 = iyp - fy0;
        const int x0 = (int)fx0, y0 = (int)fy0;
        const int xc = min(max(x0, 0), IMG_N - 1);
        const int yc = min(max(y0, 0), IMG_N - 1);

        // X-crossings walk contiguous x -> row-major P; Y-crossings walk
        // contiguous y -> col-major PT. Remap PT halves to (r0,r1) so the
        // verified composition below is shared.
        const Corner pc = isX ? P[(yc << 8) + xc] : PT[(xc << 8) + yc];
        const float2 u  = __half22float2(pc.ab);
        const float2 w2 = __half22float2(pc.cd);
        const float2 r0 = isX ? u  : make_float2(u.x, w2.x);   // (v00,v01)
        const float2 r1 = isX ? w2 : make_float2(u.y, w2.y);   // (v10,v11)

        const bool loX = (x0 == -1), loY = (y0 == -1);
        const float a  = r0.x;
        const float b2 = loX ? r0.x : r0.y;
        const float d2 = loX ? r1.x : r1.y;
        const float c3 = loY ? a  : r1.x;
        const float d3 = loY ? b2 : d2;
        const float x0v = (((unsigned)x0)       < 256u) ? 1.0f : 0.0f;
        const float x1v = (((unsigned)(x0 + 1)) < 256u) ? 1.0f : 0.0f;
        const float my0 = (((unsigned)y0)       < 256u) ? 1.0f : 0.0f;
        const float my1 = (((unsigned)(y0 + 1)) < 256u) ? 1.0f : 0.0f;
        const float wx0 = 1.0f - wx1;
        const float wy0 = (1.0f - wy1) * my0;
        const float wy1m = wy1 * my1;
        const float interp = (a * x0v * wx0 + b2 * x1v * wx1) * wy0
                           + (c3 * x0v * wx0 + d3 * x1v * wx1) * wy1m;

        acc = fmaf(wf, interp, acc);
    }

    #pragma unroll
    for (int off = 32; off > 0; off >>= 1)
        acc += __shfl_down(acc, off, 64);
    if (lane == 0)
        out[dv] = isnan(acc) ? 0.0f : acc;
}

// ---- fallback (ws too small): stream-reading kernel ----
__global__ __launch_bounds__(256) void fp_kernel_nopack(
    const float*  __restrict__ img,
    const float2* __restrict__ grid,
    const float*  __restrict__ wt,
    float*        __restrict__ out)
{
    const int wave = threadIdx.x >> 6;
    const int lane = threadIdx.x & 63;
    const int dv   = blockIdx.x * 4 + wave;
    const long base = (long)dv * NSAMP;

    float2 g[NITER];
    float  w[NITER];
    #pragma unroll
    for (int k = 0; k < NITER; ++k) {
        const int s = lane + k * 64;
        if (s < NSAMP) { g[k] = grid[base + s]; w[k] = wt[base + s]; }
        else           { g[k] = make_float2(0.0f, 0.0f); w[k] = 0.0f; }
    }
    float acc = 0.0f;
    #pragma unroll
    for (int k = 0; k < NITER; ++k) {
        const float ix = ((g[k].x + 1.0f) * 256.0f - 1.0f) * 0.5f;
        const float iy = ((g[k].y + 1.0f) * 256.0f - 1.0f) * 0.5f;
        const float fx0 = floorf(ix), fy0 = floorf(iy);
        const float wx1 = ix - fx0,  wy1 = iy - fy0;
        const int x0 = (int)fx0, y0 = (int)fy0;
        const int xc  = min(max(x0, 0), IMG_N - 2);
        const int yc0 = min(max(y0, 0), IMG_N - 1);
        const int yc1 = min(max(y0 + 1, 0), IMG_N - 1);
        const float2 p0 = *(const float2*)(img + yc0 * IMG_N + xc);
        const float2 p1 = *(const float2*)(img + yc1 * IMG_N + xc);
        const bool x0v = ((unsigned)x0) < 256u;
        const bool x1v = ((unsigned)(x0 + 1)) < 256u;
        const bool hiX = (x0 == IMG_N - 1);
        const bool loX = (x0 == -1);
        const float v00 = x0v ? (hiX ? p0.y : p0.x) : 0.0f;
        const float v01 = x1v ? (loX ? p0.x : p0.y) : 0.0f;
        const float v10 = x0v ? (hiX ? p1.y : p1.x) : 0.0f;
        const float v11 = x1v ? (loX ? p1.x : p1.y) : 0.0f;
        const float my0 = (((unsigned)y0) < 256u) ? 1.0f : 0.0f;
        const float my1 = (((unsigned)(y0 + 1)) < 256u) ? 1.0f : 0.0f;
        const float wx0 = 1.0f - wx1;
        const float wy0 = (1.0f - wy1) * my0;
        const float wy1m = wy1 * my1;
        acc += w[k] * ((v00 * wx0 + v01 * wx1) * wy0
                     + (v10 * wx0 + v11 * wx1) * wy1m);
    }
    #pragma unroll
    for (int off = 32; off > 0; off >>= 1)
        acc += __shfl_down(acc, off, 64);
    if (lane == 0) out[dv] = isnan(acc) ? 0.0f : acc;
}

extern "C" void kernel_launch(void* const* d_in, const int* in_sizes, int n_in,
                              void* d_out, int out_size, void* d_ws, size_t ws_size,
                              hipStream_t stream) {
    const float*  img  = (const float*)d_in[0];
    const float2* grid = (const float2*)d_in[1];
    const float*  wt   = (const float*)d_in[2];
    float*        out  = (float*)d_out;

    if (ws_size >= WS_NEEDED) {
        Corner* P  = (Corner*)d_ws;
        Corner* PT = (Corner*)((char*)d_ws + PT_OFF);
        float4* rt = (float4*)((char*)d_ws + RT_OFF);
        int2*   kr = (int2*)  ((char*)d_ws + KR_OFF);
        pack_kernel<<<2 * IMG_N * IMG_N / 256, 256, 0, stream>>>(img, P, PT);
        geom_kernel<<<(DV + 255) / 256, 256, 0, stream>>>(rt, kr);
        fp_siddon<<<DV / 4, 256, 0, stream>>>(P, PT, rt, kr, out);
    } else {
        fp_kernel_nopack<<<DV / 4, 256, 0, stream>>>(img, grid, wt, out);
    }
}